// Round 1
// baseline (466.169 us; speedup 1.0000x reference)
//
#include <hip/hip_runtime.h>
#include <cstdint>
#include <math.h>

// Problem constants
constexpr int NH  = 16;    // heads
constexpr int DKH = 64;    // head dim
constexpr int SEQ = 1024;  // LT == LS
constexpr int NB  = 4;     // batch
constexpr int DM  = 1024;  // d_model
constexpr int DF  = 4096;  // ffn dim

typedef __bf16 bf16;
typedef __bf16 bf16x4 __attribute__((ext_vector_type(4)));
typedef __bf16 bf16x8 __attribute__((ext_vector_type(8)));
typedef float  f32x4  __attribute__((ext_vector_type(4)));

#define MFMA16(a, b, c) __builtin_amdgcn_mfma_f32_16x16x32_bf16((a), (b), (c), 0, 0, 0)

__device__ __forceinline__ void gload_lds16(const void* g, void* l) {
  __builtin_amdgcn_global_load_lds(
      (const __attribute__((address_space(1))) unsigned int*)(uintptr_t)g,
      (__attribute__((address_space(3))) unsigned int*)(uintptr_t)l,
      16, 0, 0);
}

// ---------------- elementwise f32 -> bf16 cast ----------------
__global__ __launch_bounds__(256) void cast_kernel(const float* __restrict__ in,
                                                   bf16* __restrict__ out, int n4) {
  const int i = blockIdx.x * 256 + threadIdx.x;
  if (i >= n4) return;
  const float4 v = ((const float4*)in)[i];
  bf16x4 ov;
  ov[0] = (bf16)v.x; ov[1] = (bf16)v.y; ov[2] = (bf16)v.z; ov[3] = (bf16)v.w;
  ((bf16x4*)out)[i] = ov;
}

// ---------------- LayerNorm (f32 in, bf16 out), one block per row of D=1024 ----------------
__global__ __launch_bounds__(256) void ln_kernel(const float* __restrict__ x,
                                                 const float* __restrict__ gam,
                                                 const float* __restrict__ bet,
                                                 bf16* __restrict__ out) {
  const int row = blockIdx.x, t = threadIdx.x;
  const float4 v = ((const float4*)(x + (size_t)row * DM))[t];
  float s  = v.x + v.y + v.z + v.w;
  float s2 = v.x * v.x + v.y * v.y + v.z * v.z + v.w * v.w;
#pragma unroll
  for (int m = 1; m < 64; m <<= 1) { s += __shfl_xor(s, m); s2 += __shfl_xor(s2, m); }
  __shared__ float red[8];
  const int w = t >> 6;
  if ((t & 63) == 0) { red[w] = s; red[4 + w] = s2; }
  __syncthreads();
  s  = red[0] + red[1] + red[2] + red[3];
  s2 = red[4] + red[5] + red[6] + red[7];
  const float mean = s * (1.f / DM);
  const float var  = s2 * (1.f / DM) - mean * mean;
  const float rstd = rsqrtf(var + 1e-5f);
  const float4 g4 = ((const float4*)gam)[t];
  const float4 b4 = ((const float4*)bet)[t];
  bf16x4 ov;
  ov[0] = (bf16)((v.x - mean) * rstd * g4.x + b4.x);
  ov[1] = (bf16)((v.y - mean) * rstd * g4.y + b4.y);
  ov[2] = (bf16)((v.z - mean) * rstd * g4.z + b4.z);
  ov[3] = (bf16)((v.w - mean) * rstd * g4.w + b4.w);
  ((bf16x4*)(out + (size_t)row * DM))[t] = ov;
}

// ---------------- bf16 MFMA GEMM: out = A(MxK) * W(NxK)^T + epilogue ----------------
// A row-major K-contig; W row-major K-contig. BM=128 fixed, BN in {64,128}.
enum { EPI_Q = 0, EPI_K = 1, EPI_V = 2, EPI_O = 3, EPI_F1 = 4, EPI_F2 = 5 };

template <int MODE, int BN>
__global__ __launch_bounds__(256) void gemm_kernel(const bf16* __restrict__ A,
                                                   const bf16* __restrict__ Bw,
                                                   const float* __restrict__ bias,
                                                   const float* __restrict__ resid,
                                                   void* __restrict__ outv,
                                                   int N, int K) {
  constexpr int BM   = 128;
  constexpr int BISS = BN * 32 / 2048;            // B-tile global_load_lds issues
  constexpr int WTM  = (BN == 128) ? 64 : 32;     // wave tile rows
  constexpr int MI   = WTM / 16;
  __shared__ __align__(16) bf16 As[BM * 32];
  __shared__ __align__(16) bf16 Bs[BN * 32];
  const int t = threadIdx.x, lane = t & 63, w = t >> 6;
  const int lr = lane & 15, lg = lane >> 4;
  const int wr = (BN == 128) ? (w >> 1) : w;
  const int wc = (BN == 128) ? (w & 1) : 0;
  const int m0 = blockIdx.x * BM, n0 = blockIdx.y * BN;
  const f32x4 FZ = {0.f, 0.f, 0.f, 0.f};
  f32x4 acc[MI][4];
#pragma unroll
  for (int i = 0; i < MI; ++i)
#pragma unroll
    for (int j = 0; j < 4; ++j) acc[i][j] = FZ;

  const int nk = K >> 5;
  for (int kt = 0; kt < nk; ++kt) {
    const int k0 = kt << 5;
#pragma unroll
    for (int i = 0; i < 2; ++i) {
      const int off = (i * 256 + t) * 8;
      gload_lds16(&A[(size_t)(m0 + (off >> 5)) * K + k0 + (off & 31)], &As[off]);
    }
#pragma unroll
    for (int i = 0; i < BISS; ++i) {
      const int off = (i * 256 + t) * 8;
      gload_lds16(&Bw[(size_t)(n0 + (off >> 5)) * K + k0 + (off & 31)], &Bs[off]);
    }
    asm volatile("s_waitcnt vmcnt(0)" ::: "memory");
    __syncthreads();
    bf16x8 af[MI], bfr[4];
#pragma unroll
    for (int i = 0; i < MI; ++i)
      af[i] = *(const bf16x8*)&As[(wr * WTM + i * 16 + lr) * 32 + lg * 8];
#pragma unroll
    for (int j = 0; j < 4; ++j)
      bfr[j] = *(const bf16x8*)&Bs[(wc * 64 + j * 16 + lr) * 32 + lg * 8];
#pragma unroll
    for (int i = 0; i < MI; ++i)
#pragma unroll
      for (int j = 0; j < 4; ++j) acc[i][j] = MFMA16(af[i], bfr[j], acc[i][j]);
    __syncthreads();
  }

  // epilogue: C/D frag mapping row = 4*lg + g, col = lr (m89/m91-verified)
#pragma unroll
  for (int i = 0; i < MI; ++i) {
#pragma unroll
    for (int j = 0; j < 4; ++j) {
      const int c = n0 + wc * 64 + j * 16 + lr;
      const float bj = bias[c];
#pragma unroll
      for (int g = 0; g < 4; ++g) {
        const int r = m0 + wr * WTM + i * 16 + 4 * lg + g;  // token = l*NB + b
        float v = acc[i][j][g] + bj;
        if constexpr (MODE == EPI_Q) {
          v *= 0.125f;  // 1/sqrt(dk) folded into Q
          ((bf16*)outv)[(((size_t)((r & 3) * NH + (c >> 6)) << 10) + (r >> 2)) * DKH + (c & 63)] = (bf16)v;
        } else if constexpr (MODE == EPI_K) {
          ((bf16*)outv)[(((size_t)((r & 3) * NH + (c >> 6)) << 10) + (r >> 2)) * DKH + (c & 63)] = (bf16)v;
        } else if constexpr (MODE == EPI_V) {
          // V stored TRANSPOSED per head: (bh, d, kv) so PV B-operand is kv-contiguous
          ((bf16*)outv)[(((size_t)((r & 3) * NH + (c >> 6)) * DKH + (c & 63)) << 10) + (r >> 2)] = (bf16)v;
        } else if constexpr (MODE == EPI_O) {
          const size_t idx = (size_t)r * N + c;
          ((float*)outv)[idx] = v + resid[idx];
        } else if constexpr (MODE == EPI_F1) {
          ((bf16*)outv)[(size_t)r * N + c] = (bf16)fmaxf(v, 0.f);
        } else {  // EPI_F2
          const size_t idx = (size_t)r * N + c;
          ((float*)outv)[idx] = v + resid[idx];
        }
      }
    }
  }
}

// ---------------- flash attention: Q(bh,l,d) x K(bh,kv,d) -> softmax -> V^T(bh,d,kv) ----------------
// grid = (SEQ/128, NB*NH); 4 waves, each owns 32 q rows. KV tile = 64.
__global__ __launch_bounds__(256) void attn_kernel(const bf16* __restrict__ Qg,
                                                   const bf16* __restrict__ Kg,
                                                   const bf16* __restrict__ Vtg,
                                                   const unsigned char* __restrict__ smask,
                                                   bf16* __restrict__ Og) {
  __shared__ __align__(16) bf16 Ks[4096];      // [kc(2)][kv(64)][32] d-chunked
  __shared__ __align__(16) bf16 Vs[4096];      // [kvc(2)][d(64)][32] kv-chunked
  __shared__ __align__(16) bf16 Ps[4][2304];   // per-wave P, [32][72] padded
  const int t = threadIdx.x, lane = t & 63, w = t >> 6;
  const int lr = lane & 15, lg = lane >> 4;
  const int bh = blockIdx.y, b = bh >> 4, h = bh & 15;
  const int q0 = blockIdx.x * 128 + w * 32;
  const size_t base = (size_t)bh << 16;  // bh * SEQ * DKH

  bf16x8 qa[2][2];
#pragma unroll
  for (int m = 0; m < 2; ++m)
#pragma unroll
    for (int c = 0; c < 2; ++c)
      qa[m][c] = *(const bf16x8*)&Qg[base + (size_t)(q0 + m * 16 + lr) * DKH + c * 32 + lg * 8];

  const f32x4 FZ = {0.f, 0.f, 0.f, 0.f};
  f32x4 o[2][4];
  float mrun[2][4], lrun[2][4];
#pragma unroll
  for (int m = 0; m < 2; ++m)
#pragma unroll
    for (int g = 0; g < 4; ++g) { mrun[m][g] = -INFINITY; lrun[m][g] = 0.f; }
#pragma unroll
  for (int m = 0; m < 2; ++m)
#pragma unroll
    for (int n = 0; n < 4; ++n) o[m][n] = FZ;

  for (int kt = 0; kt < SEQ / 64; ++kt) {
    const int kv0 = kt * 64;
#pragma unroll
    for (int i = 0; i < 2; ++i) {
      const int off = (i * 256 + t) * 8;
      const int hi = off >> 11, mid = (off >> 5) & 63, lo = off & 31;
      gload_lds16(&Kg[base + (size_t)(kv0 + mid) * DKH + hi * 32 + lo], &Ks[off]);
      gload_lds16(&Vtg[base + (size_t)mid * SEQ + kv0 + hi * 32 + lo], &Vs[off]);
    }
    asm volatile("s_waitcnt vmcnt(0)" ::: "memory");
    __syncthreads();

    bf16x8 kb[4][2], vb[4][2];
#pragma unroll
    for (int n = 0; n < 4; ++n)
#pragma unroll
      for (int c = 0; c < 2; ++c) {
        kb[n][c] = *(const bf16x8*)&Ks[c * 2048 + (n * 16 + lr) * 32 + lg * 8];
        vb[n][c] = *(const bf16x8*)&Vs[c * 2048 + (n * 16 + lr) * 32 + lg * 8];
      }

    f32x4 s[2][4];
#pragma unroll
    for (int m = 0; m < 2; ++m)
#pragma unroll
      for (int n = 0; n < 4; ++n) s[m][n] = FZ;
#pragma unroll
    for (int c = 0; c < 2; ++c)
#pragma unroll
      for (int m = 0; m < 2; ++m)
#pragma unroll
        for (int n = 0; n < 4; ++n) s[m][n] = MFMA16(qa[m][c], kb[n][c], s[m][n]);

    float madd[4];
#pragma unroll
    for (int n = 0; n < 4; ++n)
      madd[n] = smask[(size_t)(kv0 + n * 16 + lr) * NB + b] ? -1e10f : 0.f;
#pragma unroll
    for (int m = 0; m < 2; ++m)
#pragma unroll
      for (int n = 0; n < 4; ++n)
#pragma unroll
        for (int g = 0; g < 4; ++g) s[m][n][g] += madd[n];

    // online softmax per row (row = q0 + m*16 + 4*lg + g; its 16 lanes differ in bits 0-3)
#pragma unroll
    for (int m = 0; m < 2; ++m) {
#pragma unroll
      for (int g = 0; g < 4; ++g) {
        float tm = fmaxf(fmaxf(s[m][0][g], s[m][1][g]), fmaxf(s[m][2][g], s[m][3][g]));
        tm = fmaxf(tm, __shfl_xor(tm, 1));
        tm = fmaxf(tm, __shfl_xor(tm, 2));
        tm = fmaxf(tm, __shfl_xor(tm, 4));
        tm = fmaxf(tm, __shfl_xor(tm, 8));
        const float mnew = fmaxf(mrun[m][g], tm);
        float ts = 0.f;
#pragma unroll
        for (int n = 0; n < 4; ++n) {
          const float p = __expf(s[m][n][g] - mnew);
          s[m][n][g] = p;
          ts += p;
        }
        ts += __shfl_xor(ts, 1);
        ts += __shfl_xor(ts, 2);
        ts += __shfl_xor(ts, 4);
        ts += __shfl_xor(ts, 8);
        const float sc = __expf(mrun[m][g] - mnew);
        lrun[m][g] = lrun[m][g] * sc + ts;
        mrun[m][g] = mnew;
#pragma unroll
        for (int n = 0; n < 4; ++n) o[m][n][g] *= sc;
      }
    }

    // P: D-fragment layout -> LDS -> A-fragment layout (bf16), padded stride 72
    bf16* Pw = &Ps[w][0];
#pragma unroll
    for (int m = 0; m < 2; ++m)
#pragma unroll
      for (int n = 0; n < 4; ++n)
#pragma unroll
        for (int g = 0; g < 4; ++g)
          Pw[(m * 16 + 4 * lg + g) * 72 + n * 16 + lr] = (bf16)s[m][n][g];
    __builtin_amdgcn_sched_barrier(0);  // keep ds_reads after ds_writes

#pragma unroll
    for (int c = 0; c < 2; ++c) {
      bf16x8 pa[2];
#pragma unroll
      for (int m = 0; m < 2; ++m)
        pa[m] = *(const bf16x8*)&Pw[(m * 16 + lr) * 72 + c * 32 + lg * 8];
#pragma unroll
      for (int m = 0; m < 2; ++m)
#pragma unroll
        for (int n = 0; n < 4; ++n) o[m][n] = MFMA16(pa[m], vb[n][c], o[m][n]);
    }
    __syncthreads();
  }

  // write attn output, token-major (l*NB+b, h*64+d), bf16
#pragma unroll
  for (int m = 0; m < 2; ++m)
#pragma unroll
    for (int g = 0; g < 4; ++g) {
      const int l = q0 + m * 16 + 4 * lg + g;
      const float inv = 1.0f / lrun[m][g];
#pragma unroll
      for (int n = 0; n < 4; ++n)
        Og[(size_t)(l * NB + b) * DM + h * 64 + n * 16 + lr] = (bf16)(o[m][n][g] * inv);
    }
}

// ---------------- host orchestration ----------------
extern "C" void kernel_launch(void* const* d_in, const int* in_sizes, int n_in,
                              void* d_out, int out_size, void* d_ws, size_t ws_size,
                              hipStream_t stream) {
  const float* enc = (const float*)d_in[0];
  const float* emb = (const float*)d_in[1];
  const unsigned char* smask = (const unsigned char*)d_in[2];
  // d_in[3] tgt_mask, d_in[4..11] mmha_*, d_in[24..25] ln0_* are dead (sublayer 0 discarded)
  const float* wq = (const float*)d_in[12]; const float* bq = (const float*)d_in[13];
  const float* wk = (const float*)d_in[14]; const float* bk = (const float*)d_in[15];
  const float* wv = (const float*)d_in[16]; const float* bv = (const float*)d_in[17];
  const float* wo = (const float*)d_in[18]; const float* bo = (const float*)d_in[19];
  const float* w1 = (const float*)d_in[20]; const float* b1 = (const float*)d_in[21];
  const float* w2 = (const float*)d_in[22]; const float* b2 = (const float*)d_in[23];
  const float* g1 = (const float*)d_in[26]; const float* be1 = (const float*)d_in[27];
  const float* g2 = (const float*)d_in[28]; const float* be2 = (const float*)d_in[29];

  char* ws = (char*)d_ws;
  const size_t MB = (size_t)1 << 20;
  bf16* wq_bf  = (bf16*)(ws + 0 * MB);
  bf16* wk_bf  = (bf16*)(ws + 2 * MB);
  bf16* wv_bf  = (bf16*)(ws + 4 * MB);
  bf16* wo_bf  = (bf16*)(ws + 6 * MB);
  bf16* w1_bf  = (bf16*)(ws + 8 * MB);
  bf16* w2_bf  = (bf16*)(ws + 16 * MB);
  bf16* enc_bf = (bf16*)(ws + 24 * MB);
  bf16* z_bf   = enc_bf;                 // alias: enc_bf dead after K/V proj
  bf16* qin_bf = (bf16*)(ws + 32 * MB);
  bf16* attn_bf = qin_bf;                // alias: qin dead after Q proj
  bf16* Q_bf   = (bf16*)(ws + 40 * MB);
  bf16* K_bf   = (bf16*)(ws + 48 * MB);
  bf16* Vt_bf  = (bf16*)(ws + 56 * MB);
  float* encdec = (float*)(ws + 64 * MB);
  bf16* h_bf   = (bf16*)(ws + 80 * MB);

  // casts (f32 -> bf16)
  cast_kernel<<<4096, 256, 0, stream>>>(enc, enc_bf, 1048576);
  cast_kernel<<<1024, 256, 0, stream>>>(wq, wq_bf, 262144);
  cast_kernel<<<1024, 256, 0, stream>>>(wk, wk_bf, 262144);
  cast_kernel<<<1024, 256, 0, stream>>>(wv, wv_bf, 262144);
  cast_kernel<<<1024, 256, 0, stream>>>(wo, wo_bf, 262144);
  cast_kernel<<<4096, 256, 0, stream>>>(w1, w1_bf, 1048576);
  cast_kernel<<<4096, 256, 0, stream>>>(w2, w2_bf, 1048576);

  // LN1(embedded) -> q_in
  ln_kernel<<<4096, 256, 0, stream>>>(emb, g1, be1, qin_bf);

  // projections (M=4096 tokens)
  gemm_kernel<EPI_Q, 64><<<dim3(32, 16), 256, 0, stream>>>(qin_bf, wq_bf, bq, nullptr, Q_bf, DM, DM);
  gemm_kernel<EPI_K, 64><<<dim3(32, 16), 256, 0, stream>>>(enc_bf, wk_bf, bk, nullptr, K_bf, DM, DM);
  gemm_kernel<EPI_V, 64><<<dim3(32, 16), 256, 0, stream>>>(enc_bf, wv_bf, bv, nullptr, Vt_bf, DM, DM);

  // flash attention
  attn_kernel<<<dim3(8, 64), 256, 0, stream>>>(Q_bf, K_bf, Vt_bf, smask, attn_bf);

  // O projection + residual(embedded) -> enc_dec (f32)
  gemm_kernel<EPI_O, 64><<<dim3(32, 16), 256, 0, stream>>>(attn_bf, wo_bf, bo, emb, encdec, DM, DM);

  // LN2(enc_dec) -> z
  ln_kernel<<<4096, 256, 0, stream>>>(encdec, g2, be2, z_bf);

  // FFN
  gemm_kernel<EPI_F1, 128><<<dim3(32, 32), 256, 0, stream>>>(z_bf, w1_bf, b1, nullptr, h_bf, DF, DM);
  gemm_kernel<EPI_F2, 64><<<dim3(32, 16), 256, 0, stream>>>(h_bf, w2_bf, b2, encdec, (float*)d_out, DM, DF);
}

// Round 2
// 398.737 us; speedup vs baseline: 1.1691x; 1.1691x over previous
//
#include <hip/hip_runtime.h>
#include <cstdint>
#include <math.h>

// Problem constants
constexpr int NH  = 16;    // heads
constexpr int DKH = 64;    // head dim
constexpr int SEQ = 1024;  // LT == LS
constexpr int NB  = 4;     // batch
constexpr int DM  = 1024;  // d_model
constexpr int DF  = 4096;  // ffn dim

typedef __bf16 bf16;
typedef __bf16 bf16x4 __attribute__((ext_vector_type(4)));
typedef __bf16 bf16x8 __attribute__((ext_vector_type(8)));
typedef float  f32x4  __attribute__((ext_vector_type(4)));

#define MFMA16(a, b, c) __builtin_amdgcn_mfma_f32_16x16x32_bf16((a), (b), (c), 0, 0, 0)

__device__ __forceinline__ void gload_lds16(const void* g, void* l) {
  __builtin_amdgcn_global_load_lds(
      (const __attribute__((address_space(1))) unsigned int*)(uintptr_t)g,
      (__attribute__((address_space(3))) unsigned int*)(uintptr_t)l,
      16, 0, 0);
}

// LDS 16B-chunk swizzle: XOR chunk index with row bits so that a wave's 16
// row-consecutive ds_read_b128 spread across banks (2-way max = free, m136).
// Staging pre-swizzles the GLOBAL source; LDS dest stays linear (rule #21).
template <int BK>
__device__ __forceinline__ int swz(int row) {
  return (BK == 32) ? ((row >> 1) & 3) : (row & 7);
}

// stage ROWS x BK bf16 tile (row-major, ldg stride) into LDS, 256 threads
template <int ROWS, int BK>
__device__ __forceinline__ void stage_tile(const bf16* __restrict__ g, int ldg,
                                           bf16* __restrict__ l, int t) {
  constexpr int ITER = ROWS * BK / 2048;
#pragma unroll
  for (int i = 0; i < ITER; ++i) {
    const int off = (i * 256 + t) * 8;
    const int row = off / BK;
    const int cc = (off & (BK - 1)) >> 3;
    const int sc = cc ^ swz<BK>(row);
    gload_lds16(&g[(size_t)row * ldg + (sc << 3)], &l[off]);
  }
}

// ---------------- fused casts (f32 -> bf16) ----------------
__global__ __launch_bounds__(256) void cast4_kernel(const float* __restrict__ i0, const float* __restrict__ i1,
                                                    const float* __restrict__ i2, const float* __restrict__ i3,
                                                    bf16* __restrict__ o0, bf16* __restrict__ o1,
                                                    bf16* __restrict__ o2, bf16* __restrict__ o3) {
  const int sel = blockIdx.x >> 10;                       // 4 segments x 1024 blocks
  const int idx = (blockIdx.x & 1023) * 256 + threadIdx.x;  // 262144 float4 each
  const float* in = sel == 0 ? i0 : sel == 1 ? i1 : sel == 2 ? i2 : i3;
  bf16* out = sel == 0 ? o0 : sel == 1 ? o1 : sel == 2 ? o2 : o3;
  const float4 v = ((const float4*)in)[idx];
  bf16x4 ov;
  ov[0] = (bf16)v.x; ov[1] = (bf16)v.y; ov[2] = (bf16)v.z; ov[3] = (bf16)v.w;
  ((bf16x4*)out)[idx] = ov;
}

__global__ __launch_bounds__(256) void cast3_kernel(const float* __restrict__ i0, const float* __restrict__ i1,
                                                    const float* __restrict__ i2,
                                                    bf16* __restrict__ o0, bf16* __restrict__ o1,
                                                    bf16* __restrict__ o2) {
  const int sel = blockIdx.x >> 12;                        // 3 segments x 4096 blocks
  const int idx = (blockIdx.x & 4095) * 256 + threadIdx.x; // 1048576 float4 each
  const float* in = sel == 0 ? i0 : sel == 1 ? i1 : i2;
  bf16* out = sel == 0 ? o0 : sel == 1 ? o1 : o2;
  const float4 v = ((const float4*)in)[idx];
  bf16x4 ov;
  ov[0] = (bf16)v.x; ov[1] = (bf16)v.y; ov[2] = (bf16)v.z; ov[3] = (bf16)v.w;
  ((bf16x4*)out)[idx] = ov;
}

// ---------------- LayerNorm (f32 in, bf16 out), one block per row of D=1024 ----------------
__global__ __launch_bounds__(256) void ln_kernel(const float* __restrict__ x,
                                                 const float* __restrict__ gam,
                                                 const float* __restrict__ bet,
                                                 bf16* __restrict__ out) {
  const int row = blockIdx.x, t = threadIdx.x;
  const float4 v = ((const float4*)(x + (size_t)row * DM))[t];
  float s  = v.x + v.y + v.z + v.w;
  float s2 = v.x * v.x + v.y * v.y + v.z * v.z + v.w * v.w;
#pragma unroll
  for (int m = 1; m < 64; m <<= 1) { s += __shfl_xor(s, m); s2 += __shfl_xor(s2, m); }
  __shared__ float red[8];
  const int w = t >> 6;
  if ((t & 63) == 0) { red[w] = s; red[4 + w] = s2; }
  __syncthreads();
  s  = red[0] + red[1] + red[2] + red[3];
  s2 = red[4] + red[5] + red[6] + red[7];
  const float mean = s * (1.f / DM);
  const float var  = s2 * (1.f / DM) - mean * mean;
  const float rstd = rsqrtf(var + 1e-5f);
  const float4 g4 = ((const float4*)gam)[t];
  const float4 b4 = ((const float4*)bet)[t];
  bf16x4 ov;
  ov[0] = (bf16)((v.x - mean) * rstd * g4.x + b4.x);
  ov[1] = (bf16)((v.y - mean) * rstd * g4.y + b4.y);
  ov[2] = (bf16)((v.z - mean) * rstd * g4.z + b4.z);
  ov[3] = (bf16)((v.w - mean) * rstd * g4.w + b4.w);
  ((bf16x4*)(out + (size_t)row * DM))[t] = ov;
}

// ---------------- bf16 MFMA GEMM v2: prefetch double-buffer + swizzled LDS ----------------
enum { EPI_QKV = 0, EPI_O = 3, EPI_F1 = 4, EPI_F2 = 5 };

struct GParams {
  const bf16* A;    // A operand (M x K, K-contig)
  const bf16* A2;   // QKV: A for n0 >= 1024 (enc)
  const bf16* W;    // weights (N x K, K-contig)
  const float* b0;  // bias (QKV: bq)
  const float* b1;  // QKV: bk
  const float* b2;  // QKV: bv
  const float* resid;
  void* out;        // QKV: Q
  void* out1;       // QKV: K
  void* out2;       // QKV: V^T
  int N;
  int K;
};

template <int MODE, int BN, int BK>
__global__ __launch_bounds__(256, 3) void gemm2(GParams p) {
  constexpr int BM = 128;
  constexpr int WTM = (BN == 128) ? 64 : 32;  // wave tile rows
  constexpr int MI = WTM / 16;
  __shared__ __align__(16) bf16 As[2][BM * BK];
  __shared__ __align__(16) bf16 Bs[2][BN * BK];
  const int t = threadIdx.x, lane = t & 63, w = t >> 6;
  const int lr = lane & 15, lg = lane >> 4;
  const int wr = (BN == 128) ? (w >> 1) : w;
  const int wc = (BN == 128) ? (w & 1) : 0;
  const int m0 = blockIdx.x * BM, n0 = blockIdx.y * BN;
  const bf16* Ap = (MODE == EPI_QKV && n0 >= 1024) ? p.A2 : p.A;
  const f32x4 FZ = {0.f, 0.f, 0.f, 0.f};
  f32x4 acc[MI][4];
#pragma unroll
  for (int i = 0; i < MI; ++i)
#pragma unroll
    for (int j = 0; j < 4; ++j) acc[i][j] = FZ;

  const int nk = p.K / BK;
  // prologue: stage tile 0
  stage_tile<BM, BK>(&Ap[(size_t)m0 * p.K], p.K, As[0], t);
  stage_tile<BN, BK>(&p.W[(size_t)n0 * p.K], p.K, Bs[0], t);
  asm volatile("s_waitcnt vmcnt(0)" ::: "memory");
  __syncthreads();

  int cur = 0;
  for (int kt = 0; kt < nk; ++kt) {
    // prefetch next tile into the other buffer (loads fly during compute)
    if (kt + 1 < nk) {
      stage_tile<BM, BK>(&Ap[(size_t)m0 * p.K + (size_t)(kt + 1) * BK], p.K, As[cur ^ 1], t);
      stage_tile<BN, BK>(&p.W[(size_t)n0 * p.K + (size_t)(kt + 1) * BK], p.K, Bs[cur ^ 1], t);
    }
    const bf16* Asl = As[cur];
    const bf16* Bsl = Bs[cur];
#pragma unroll
    for (int kh = 0; kh < BK / 32; ++kh) {
      bf16x8 af[MI], bfr[4];
#pragma unroll
      for (int i = 0; i < MI; ++i) {
        const int row = wr * WTM + i * 16 + lr;
        const int c = (kh * 4 + lg) ^ swz<BK>(row);
        af[i] = *(const bf16x8*)&Asl[row * BK + c * 8];
      }
#pragma unroll
      for (int j = 0; j < 4; ++j) {
        const int row = wc * 64 + j * 16 + lr;
        const int c = (kh * 4 + lg) ^ swz<BK>(row);
        bfr[j] = *(const bf16x8*)&Bsl[row * BK + c * 8];
      }
#pragma unroll
      for (int i = 0; i < MI; ++i)
#pragma unroll
        for (int j = 0; j < 4; ++j) acc[i][j] = MFMA16(af[i], bfr[j], acc[i][j]);
    }
    // one drain+barrier per K-tile: waits prefetched stages AND this tile's ds_reads
    asm volatile("s_waitcnt vmcnt(0)" ::: "memory");
    __syncthreads();
    cur ^= 1;
  }

  // epilogue: C/D frag mapping row = 4*lg + g, col = lr (m89/m91-verified)
#pragma unroll
  for (int i = 0; i < MI; ++i) {
#pragma unroll
    for (int j = 0; j < 4; ++j) {
      const int c = n0 + wc * 64 + j * 16 + lr;
      float bj;
      if constexpr (MODE == EPI_QKV)
        bj = (c < 1024 ? p.b0 : c < 2048 ? p.b1 : p.b2)[c & 1023];
      else
        bj = p.b0[c];
#pragma unroll
      for (int g = 0; g < 4; ++g) {
        const int r = m0 + wr * WTM + i * 16 + 4 * lg + g;  // token = l*NB + b
        float v = acc[i][j][g] + bj;
        if constexpr (MODE == EPI_QKV) {
          const int cl = c & 1023;
          const size_t sidx = (((size_t)((r & 3) * NH + (cl >> 6)) << 10) + (r >> 2)) * DKH + (cl & 63);
          if (c < 1024)
            ((bf16*)p.out)[sidx] = (bf16)(v * 0.125f);  // 1/sqrt(dk) folded into Q
          else if (c < 2048)
            ((bf16*)p.out1)[sidx] = (bf16)v;
          else  // V stored TRANSPOSED per head: (bh, d, kv)
            ((bf16*)p.out2)[(((size_t)((r & 3) * NH + (cl >> 6)) * DKH + (cl & 63)) << 10) + (r >> 2)] = (bf16)v;
        } else if constexpr (MODE == EPI_O) {
          const size_t idx = (size_t)r * p.N + c;
          ((float*)p.out)[idx] = v + p.resid[idx];
        } else if constexpr (MODE == EPI_F1) {
          ((bf16*)p.out)[(size_t)r * p.N + c] = (bf16)fmaxf(v, 0.f);
        } else {  // EPI_F2
          const size_t idx = (size_t)r * p.N + c;
          ((float*)p.out)[idx] = v + p.resid[idx];
        }
      }
    }
  }
}

// ---------------- flash attention: Q(bh,l,d) x K(bh,kv,d) -> softmax -> V^T(bh,d,kv) ----------------
__global__ __launch_bounds__(256) void attn_kernel(const bf16* __restrict__ Qg,
                                                   const bf16* __restrict__ Kg,
                                                   const bf16* __restrict__ Vtg,
                                                   const unsigned char* __restrict__ smask,
                                                   bf16* __restrict__ Og) {
  __shared__ __align__(16) bf16 Ks[4096];      // [kc(2)][kv(64)][32] d-chunked
  __shared__ __align__(16) bf16 Vs[4096];      // [kvc(2)][d(64)][32] kv-chunked
  __shared__ __align__(16) bf16 Ps[4][2304];   // per-wave P, [32][72] padded
  const int t = threadIdx.x, lane = t & 63, w = t >> 6;
  const int lr = lane & 15, lg = lane >> 4;
  const int bh = blockIdx.y, b = bh >> 4, h = bh & 15;
  const int q0 = blockIdx.x * 128 + w * 32;
  const size_t base = (size_t)bh << 16;  // bh * SEQ * DKH

  bf16x8 qa[2][2];
#pragma unroll
  for (int m = 0; m < 2; ++m)
#pragma unroll
    for (int c = 0; c < 2; ++c)
      qa[m][c] = *(const bf16x8*)&Qg[base + (size_t)(q0 + m * 16 + lr) * DKH + c * 32 + lg * 8];

  const f32x4 FZ = {0.f, 0.f, 0.f, 0.f};
  f32x4 o[2][4];
  float mrun[2][4], lrun[2][4];
#pragma unroll
  for (int m = 0; m < 2; ++m)
#pragma unroll
    for (int g = 0; g < 4; ++g) { mrun[m][g] = -INFINITY; lrun[m][g] = 0.f; }
#pragma unroll
  for (int m = 0; m < 2; ++m)
#pragma unroll
    for (int n = 0; n < 4; ++n) o[m][n] = FZ;

  for (int kt = 0; kt < SEQ / 64; ++kt) {
    const int kv0 = kt * 64;
#pragma unroll
    for (int i = 0; i < 2; ++i) {
      const int off = (i * 256 + t) * 8;
      const int hi = off >> 11, mid = (off >> 5) & 63, lo = off & 31;
      gload_lds16(&Kg[base + (size_t)(kv0 + mid) * DKH + hi * 32 + lo], &Ks[off]);
      gload_lds16(&Vtg[base + (size_t)mid * SEQ + kv0 + hi * 32 + lo], &Vs[off]);
    }
    asm volatile("s_waitcnt vmcnt(0)" ::: "memory");
    __syncthreads();

    bf16x8 kb[4][2], vb[4][2];
#pragma unroll
    for (int n = 0; n < 4; ++n)
#pragma unroll
      for (int c = 0; c < 2; ++c) {
        kb[n][c] = *(const bf16x8*)&Ks[c * 2048 + (n * 16 + lr) * 32 + lg * 8];
        vb[n][c] = *(const bf16x8*)&Vs[c * 2048 + (n * 16 + lr) * 32 + lg * 8];
      }

    f32x4 s[2][4];
#pragma unroll
    for (int m = 0; m < 2; ++m)
#pragma unroll
      for (int n = 0; n < 4; ++n) s[m][n] = FZ;
#pragma unroll
    for (int c = 0; c < 2; ++c)
#pragma unroll
      for (int m = 0; m < 2; ++m)
#pragma unroll
        for (int n = 0; n < 4; ++n) s[m][n] = MFMA16(qa[m][c], kb[n][c], s[m][n]);

    float madd[4];
#pragma unroll
    for (int n = 0; n < 4; ++n)
      madd[n] = smask[(size_t)(kv0 + n * 16 + lr) * NB + b] ? -1e10f : 0.f;
#pragma unroll
    for (int m = 0; m < 2; ++m)
#pragma unroll
      for (int n = 0; n < 4; ++n)
#pragma unroll
        for (int g = 0; g < 4; ++g) s[m][n][g] += madd[n];

    // online softmax per row (row's 16 lanes differ in lane bits 0-3)
#pragma unroll
    for (int m = 0; m < 2; ++m) {
#pragma unroll
      for (int g = 0; g < 4; ++g) {
        float tm = fmaxf(fmaxf(s[m][0][g], s[m][1][g]), fmaxf(s[m][2][g], s[m][3][g]));
        tm = fmaxf(tm, __shfl_xor(tm, 1));
        tm = fmaxf(tm, __shfl_xor(tm, 2));
        tm = fmaxf(tm, __shfl_xor(tm, 4));
        tm = fmaxf(tm, __shfl_xor(tm, 8));
        const float mnew = fmaxf(mrun[m][g], tm);
        float ts = 0.f;
#pragma unroll
        for (int n = 0; n < 4; ++n) {
          const float p = __expf(s[m][n][g] - mnew);
          s[m][n][g] = p;
          ts += p;
        }
        ts += __shfl_xor(ts, 1);
        ts += __shfl_xor(ts, 2);
        ts += __shfl_xor(ts, 4);
        ts += __shfl_xor(ts, 8);
        const float sc = __expf(mrun[m][g] - mnew);
        lrun[m][g] = lrun[m][g] * sc + ts;
        mrun[m][g] = mnew;
#pragma unroll
        for (int n = 0; n < 4; ++n) o[m][n][g] *= sc;
      }
    }

    // P: D-fragment layout -> LDS -> A-fragment layout (bf16), padded stride 72
    bf16* Pw = &Ps[w][0];
#pragma unroll
    for (int m = 0; m < 2; ++m)
#pragma unroll
      for (int n = 0; n < 4; ++n)
#pragma unroll
        for (int g = 0; g < 4; ++g)
          Pw[(m * 16 + 4 * lg + g) * 72 + n * 16 + lr] = (bf16)s[m][n][g];
    __builtin_amdgcn_sched_barrier(0);  // keep ds_reads after ds_writes

#pragma unroll
    for (int c = 0; c < 2; ++c) {
      bf16x8 pa[2];
#pragma unroll
      for (int m = 0; m < 2; ++m)
        pa[m] = *(const bf16x8*)&Pw[(m * 16 + lr) * 72 + c * 32 + lg * 8];
#pragma unroll
      for (int m = 0; m < 2; ++m)
#pragma unroll
        for (int n = 0; n < 4; ++n) o[m][n] = MFMA16(pa[m], vb[n][c], o[m][n]);
    }
    __syncthreads();
  }

  // write attn output, token-major (l*NB+b, h*64+d), bf16
#pragma unroll
  for (int m = 0; m < 2; ++m)
#pragma unroll
    for (int g = 0; g < 4; ++g) {
      const int l = q0 + m * 16 + 4 * lg + g;
      const float inv = 1.0f / lrun[m][g];
#pragma unroll
      for (int n = 0; n < 4; ++n)
        Og[(size_t)(l * NB + b) * DM + h * 64 + n * 16 + lr] = (bf16)(o[m][n][g] * inv);
    }
}

// ---------------- host orchestration ----------------
extern "C" void kernel_launch(void* const* d_in, const int* in_sizes, int n_in,
                              void* d_out, int out_size, void* d_ws, size_t ws_size,
                              hipStream_t stream) {
  const float* enc = (const float*)d_in[0];
  const float* emb = (const float*)d_in[1];
  const unsigned char* smask = (const unsigned char*)d_in[2];
  // d_in[3] tgt_mask, d_in[4..11] mmha_*, d_in[24..25] ln0_* are dead (sublayer 0 discarded)
  const float* wq = (const float*)d_in[12]; const float* bq = (const float*)d_in[13];
  const float* wk = (const float*)d_in[14]; const float* bk = (const float*)d_in[15];
  const float* wv = (const float*)d_in[16]; const float* bv = (const float*)d_in[17];
  const float* wo = (const float*)d_in[18]; const float* bo = (const float*)d_in[19];
  const float* w1 = (const float*)d_in[20]; const float* b1 = (const float*)d_in[21];
  const float* w2 = (const float*)d_in[22]; const float* b2 = (const float*)d_in[23];
  const float* g1 = (const float*)d_in[26]; const float* be1 = (const float*)d_in[27];
  const float* g2 = (const float*)d_in[28]; const float* be2 = (const float*)d_in[29];

  char* ws = (char*)d_ws;
  const size_t MB = (size_t)1 << 20;
  bf16* wqkv_bf = (bf16*)(ws + 0 * MB);   // 3072x1024 packed (Q|K|V)
  bf16* wo_bf   = (bf16*)(ws + 6 * MB);
  bf16* w1_bf   = (bf16*)(ws + 8 * MB);
  bf16* w2_bf   = (bf16*)(ws + 16 * MB);
  bf16* enc_bf  = (bf16*)(ws + 24 * MB);
  bf16* z_bf    = enc_bf;                 // alias: enc_bf dead after QKV proj
  bf16* qin_bf  = (bf16*)(ws + 32 * MB);
  bf16* attn_bf = qin_bf;                 // alias: qin dead after QKV proj
  bf16* Q_bf    = (bf16*)(ws + 40 * MB);
  bf16* K_bf    = (bf16*)(ws + 48 * MB);
  bf16* Vt_bf   = (bf16*)(ws + 56 * MB);
  float* encdec = (float*)(ws + 64 * MB);
  bf16* h_bf    = (bf16*)(ws + 80 * MB);

  // casts (f32 -> bf16): wq|wk|wv packed into wqkv, wo separate; w1, w2, enc
  cast4_kernel<<<4096, 256, 0, stream>>>(wq, wk, wv, wo,
                                         wqkv_bf, wqkv_bf + (1 << 20), wqkv_bf + (2 << 20), wo_bf);
  cast3_kernel<<<12288, 256, 0, stream>>>(w1, w2, enc, w1_bf, w2_bf, enc_bf);

  // LN1(embedded) -> q_in
  ln_kernel<<<4096, 256, 0, stream>>>(emb, g1, be1, qin_bf);

  // fused Q|K|V projection: N=3072, grid (32,24)=768 blocks (3/CU)
  {
    GParams p{qin_bf, enc_bf, wqkv_bf, bq, bk, bv, nullptr, Q_bf, K_bf, Vt_bf, 3072, DM};
    gemm2<EPI_QKV, 128, 32><<<dim3(32, 24), 256, 0, stream>>>(p);
  }

  // flash attention
  attn_kernel<<<dim3(8, 64), 256, 0, stream>>>(Q_bf, K_bf, Vt_bf, smask, attn_bf);

  // O projection + residual(embedded) -> enc_dec (f32)
  {
    GParams p{attn_bf, nullptr, wo_bf, bo, nullptr, nullptr, emb, encdec, nullptr, nullptr, DM, DM};
    gemm2<EPI_O, 64, 64><<<dim3(32, 16), 256, 0, stream>>>(p);
  }

  // LN2(enc_dec) -> z
  ln_kernel<<<4096, 256, 0, stream>>>(encdec, g2, be2, z_bf);

  // FFN
  {
    GParams p{z_bf, nullptr, w1_bf, b1, nullptr, nullptr, nullptr, h_bf, nullptr, nullptr, DF, DM};
    gemm2<EPI_F1, 128, 32><<<dim3(32, 32), 256, 0, stream>>>(p);
  }
  {
    GParams p{h_bf, nullptr, w2_bf, b2, nullptr, nullptr, encdec, d_out, nullptr, nullptr, DM, DF};
    gemm2<EPI_F2, 64, 64><<<dim3(32, 16), 256, 0, stream>>>(p);
  }
}

// Round 3
// 388.304 us; speedup vs baseline: 1.2005x; 1.0269x over previous
//
#include <hip/hip_runtime.h>
#include <cstdint>
#include <math.h>

// Problem constants
constexpr int NH  = 16;    // heads
constexpr int DKH = 64;    // head dim
constexpr int SEQ = 1024;  // LT == LS
constexpr int NB  = 4;     // batch
constexpr int DM  = 1024;  // d_model
constexpr int DF  = 4096;  // ffn dim

typedef __bf16 bf16;
typedef __bf16 bf16x4 __attribute__((ext_vector_type(4)));
typedef __bf16 bf16x8 __attribute__((ext_vector_type(8)));
typedef float  f32x4  __attribute__((ext_vector_type(4)));

#define MFMA16(a, b, c) __builtin_amdgcn_mfma_f32_16x16x32_bf16((a), (b), (c), 0, 0, 0)

__device__ __forceinline__ void gload_lds16(const void* g, void* l) {
  __builtin_amdgcn_global_load_lds(
      (const __attribute__((address_space(1))) unsigned int*)(uintptr_t)g,
      (__attribute__((address_space(3))) unsigned int*)(uintptr_t)l,
      16, 0, 0);
}

// LDS 16B-chunk swizzle: XOR chunk index with row bits so that a wave's 16
// row-consecutive ds_read_b128 spread across banks (2-way max = free, m136).
// Staging pre-swizzles the GLOBAL source; LDS dest stays linear (rule #21).
template <int BK>
__device__ __forceinline__ int swz(int row) {
  return (BK == 32) ? ((row >> 1) & 3) : (row & 7);
}

// stage ROWS x BK bf16 tile (row-major, ldg stride) into LDS, 256 threads
template <int ROWS, int BK>
__device__ __forceinline__ void stage_tile(const bf16* __restrict__ g, int ldg,
                                           bf16* __restrict__ l, int t) {
  constexpr int ITER = ROWS * BK / 2048;
#pragma unroll
  for (int i = 0; i < ITER; ++i) {
    const int off = (i * 256 + t) * 8;
    const int row = off / BK;
    const int cc = (off & (BK - 1)) >> 3;
    const int sc = cc ^ swz<BK>(row);
    gload_lds16(&g[(size_t)row * ldg + (sc << 3)], &l[off]);
  }
}

// ---------------- fused casts (f32 -> bf16) ----------------
__global__ __launch_bounds__(256) void cast4_kernel(const float* __restrict__ i0, const float* __restrict__ i1,
                                                    const float* __restrict__ i2, const float* __restrict__ i3,
                                                    bf16* __restrict__ o0, bf16* __restrict__ o1,
                                                    bf16* __restrict__ o2, bf16* __restrict__ o3) {
  const int sel = blockIdx.x >> 10;                       // 4 segments x 1024 blocks
  const int idx = (blockIdx.x & 1023) * 256 + threadIdx.x;  // 262144 float4 each
  const float* in = sel == 0 ? i0 : sel == 1 ? i1 : sel == 2 ? i2 : i3;
  bf16* out = sel == 0 ? o0 : sel == 1 ? o1 : sel == 2 ? o2 : o3;
  const float4 v = ((const float4*)in)[idx];
  bf16x4 ov;
  ov[0] = (bf16)v.x; ov[1] = (bf16)v.y; ov[2] = (bf16)v.z; ov[3] = (bf16)v.w;
  ((bf16x4*)out)[idx] = ov;
}

__global__ __launch_bounds__(256) void cast3_kernel(const float* __restrict__ i0, const float* __restrict__ i1,
                                                    const float* __restrict__ i2,
                                                    bf16* __restrict__ o0, bf16* __restrict__ o1,
                                                    bf16* __restrict__ o2) {
  const int sel = blockIdx.x >> 12;                        // 3 segments x 4096 blocks
  const int idx = (blockIdx.x & 4095) * 256 + threadIdx.x; // 1048576 float4 each
  const float* in = sel == 0 ? i0 : sel == 1 ? i1 : i2;
  bf16* out = sel == 0 ? o0 : sel == 1 ? o1 : o2;
  const float4 v = ((const float4*)in)[idx];
  bf16x4 ov;
  ov[0] = (bf16)v.x; ov[1] = (bf16)v.y; ov[2] = (bf16)v.z; ov[3] = (bf16)v.w;
  ((bf16x4*)out)[idx] = ov;
}

// ---------------- LayerNorm (f32 in, bf16 out), one block per row of D=1024 ----------------
__global__ __launch_bounds__(256) void ln_kernel(const float* __restrict__ x,
                                                 const float* __restrict__ gam,
                                                 const float* __restrict__ bet,
                                                 bf16* __restrict__ out) {
  const int row = blockIdx.x, t = threadIdx.x;
  const float4 v = ((const float4*)(x + (size_t)row * DM))[t];
  float s  = v.x + v.y + v.z + v.w;
  float s2 = v.x * v.x + v.y * v.y + v.z * v.z + v.w * v.w;
#pragma unroll
  for (int m = 1; m < 64; m <<= 1) { s += __shfl_xor(s, m); s2 += __shfl_xor(s2, m); }
  __shared__ float red[8];
  const int w = t >> 6;
  if ((t & 63) == 0) { red[w] = s; red[4 + w] = s2; }
  __syncthreads();
  s  = red[0] + red[1] + red[2] + red[3];
  s2 = red[4] + red[5] + red[6] + red[7];
  const float mean = s * (1.f / DM);
  const float var  = s2 * (1.f / DM) - mean * mean;
  const float rstd = rsqrtf(var + 1e-5f);
  const float4 g4 = ((const float4*)gam)[t];
  const float4 b4 = ((const float4*)bet)[t];
  bf16x4 ov;
  ov[0] = (bf16)((v.x - mean) * rstd * g4.x + b4.x);
  ov[1] = (bf16)((v.y - mean) * rstd * g4.y + b4.y);
  ov[2] = (bf16)((v.z - mean) * rstd * g4.z + b4.z);
  ov[3] = (bf16)((v.w - mean) * rstd * g4.w + b4.w);
  ((bf16x4*)(out + (size_t)row * DM))[t] = ov;
}

// ---------------- bf16 MFMA GEMM v2: prefetch double-buffer + swizzled LDS ----------------
enum { EPI_QKV = 0, EPI_O = 3, EPI_F1 = 4, EPI_F2 = 5 };

struct GParams {
  const bf16* A;    // A operand (M x K, K-contig)
  const bf16* A2;   // QKV: A for n0 >= 1024 (enc)
  const bf16* W;    // weights (N x K, K-contig)
  const float* b0;  // bias (QKV: bq)
  const float* b1;  // QKV: bk
  const float* b2;  // QKV: bv
  const float* resid;
  void* out;        // QKV: Q
  void* out1;       // QKV: K
  void* out2;       // QKV: V^T
  int N;
  int K;
};

template <int MODE, int BN, int BK>
__global__ __launch_bounds__(256, 3) void gemm2(GParams p) {
  constexpr int BM = 128;
  constexpr int WTM = (BN == 128) ? 64 : 32;  // wave tile rows
  constexpr int MI = WTM / 16;
  __shared__ __align__(16) bf16 As[2][BM * BK];
  __shared__ __align__(16) bf16 Bs[2][BN * BK];
  const int t = threadIdx.x, lane = t & 63, w = t >> 6;
  const int lr = lane & 15, lg = lane >> 4;
  const int wr = (BN == 128) ? (w >> 1) : w;
  const int wc = (BN == 128) ? (w & 1) : 0;
  const int m0 = blockIdx.x * BM, n0 = blockIdx.y * BN;
  const bf16* Ap = (MODE == EPI_QKV && n0 >= 1024) ? p.A2 : p.A;
  const f32x4 FZ = {0.f, 0.f, 0.f, 0.f};
  f32x4 acc[MI][4];
#pragma unroll
  for (int i = 0; i < MI; ++i)
#pragma unroll
    for (int j = 0; j < 4; ++j) acc[i][j] = FZ;

  const int nk = p.K / BK;
  // prologue: stage tile 0
  stage_tile<BM, BK>(&Ap[(size_t)m0 * p.K], p.K, As[0], t);
  stage_tile<BN, BK>(&p.W[(size_t)n0 * p.K], p.K, Bs[0], t);
  asm volatile("s_waitcnt vmcnt(0)" ::: "memory");
  __syncthreads();

  int cur = 0;
  for (int kt = 0; kt < nk; ++kt) {
    // prefetch next tile into the other buffer (loads fly during compute)
    if (kt + 1 < nk) {
      stage_tile<BM, BK>(&Ap[(size_t)m0 * p.K + (size_t)(kt + 1) * BK], p.K, As[cur ^ 1], t);
      stage_tile<BN, BK>(&p.W[(size_t)n0 * p.K + (size_t)(kt + 1) * BK], p.K, Bs[cur ^ 1], t);
    }
    const bf16* Asl = As[cur];
    const bf16* Bsl = Bs[cur];
#pragma unroll
    for (int kh = 0; kh < BK / 32; ++kh) {
      bf16x8 af[MI], bfr[4];
#pragma unroll
      for (int i = 0; i < MI; ++i) {
        const int row = wr * WTM + i * 16 + lr;
        const int c = (kh * 4 + lg) ^ swz<BK>(row);
        af[i] = *(const bf16x8*)&Asl[row * BK + c * 8];
      }
#pragma unroll
      for (int j = 0; j < 4; ++j) {
        const int row = wc * 64 + j * 16 + lr;
        const int c = (kh * 4 + lg) ^ swz<BK>(row);
        bfr[j] = *(const bf16x8*)&Bsl[row * BK + c * 8];
      }
#pragma unroll
      for (int i = 0; i < MI; ++i)
#pragma unroll
        for (int j = 0; j < 4; ++j) acc[i][j] = MFMA16(af[i], bfr[j], acc[i][j]);
    }
    // one drain+barrier per K-tile: waits prefetched stages AND this tile's ds_reads
    asm volatile("s_waitcnt vmcnt(0)" ::: "memory");
    __syncthreads();
    cur ^= 1;
  }

  // epilogue: C/D frag mapping row = 4*lg + g, col = lr (m89/m91-verified)
#pragma unroll
  for (int i = 0; i < MI; ++i) {
#pragma unroll
    for (int j = 0; j < 4; ++j) {
      const int c = n0 + wc * 64 + j * 16 + lr;
      float bj;
      if constexpr (MODE == EPI_QKV)
        bj = (c < 1024 ? p.b0 : c < 2048 ? p.b1 : p.b2)[c & 1023];
      else
        bj = p.b0[c];
#pragma unroll
      for (int g = 0; g < 4; ++g) {
        const int r = m0 + wr * WTM + i * 16 + 4 * lg + g;  // token = l*NB + b
        float v = acc[i][j][g] + bj;
        if constexpr (MODE == EPI_QKV) {
          const int cl = c & 1023;
          const size_t sidx = (((size_t)((r & 3) * NH + (cl >> 6)) << 10) + (r >> 2)) * DKH + (cl & 63);
          if (c < 1024)
            ((bf16*)p.out)[sidx] = (bf16)(v * 0.125f);  // 1/sqrt(dk) folded into Q
          else if (c < 2048)
            ((bf16*)p.out1)[sidx] = (bf16)v;
          else  // V stored TRANSPOSED per head: (bh, d, kv)
            ((bf16*)p.out2)[(((size_t)((r & 3) * NH + (cl >> 6)) * DKH + (cl & 63)) << 10) + (r >> 2)] = (bf16)v;
        } else if constexpr (MODE == EPI_O) {
          const size_t idx = (size_t)r * p.N + c;
          ((float*)p.out)[idx] = v + p.resid[idx];
        } else if constexpr (MODE == EPI_F1) {
          ((bf16*)p.out)[(size_t)r * p.N + c] = (bf16)fmaxf(v, 0.f);
        } else {  // EPI_F2
          const size_t idx = (size_t)r * p.N + c;
          ((float*)p.out)[idx] = v + p.resid[idx];
        }
      }
    }
  }
}

// ---------------- flash attention v2 ----------------
// 512 threads = 8 waves, each owning 16 q rows; KV tile 64, double-buffered
// prefetch; XCD-swizzled 1-D grid so all 8 q-tiles of a head share id%8
// (same XCD L2 -> K/V fetched once per XCD).
__global__ __launch_bounds__(512, 4) void attn_kernel(const bf16* __restrict__ Qg,
                                                      const bf16* __restrict__ Kg,
                                                      const bf16* __restrict__ Vtg,
                                                      const unsigned char* __restrict__ smask,
                                                      bf16* __restrict__ Og) {
  __shared__ __align__(16) bf16 Ks[2][4096];   // [buf][kc(2)][kv(64)][32] d-chunked
  __shared__ __align__(16) bf16 Vs[2][4096];   // [buf][kvc(2)][d(64)][32] kv-chunked
  __shared__ __align__(16) bf16 Ps[8][1152];   // per-wave P, [16][72] padded
  const int t = threadIdx.x, lane = t & 63, w = t >> 6;
  const int lr = lane & 15, lg = lane >> 4;
  // work mapping: id = a*64 + qt*8 + r, bh = a*8 + r  (id%8 == bh%8 -> XCD share)
  const int id = blockIdx.x;
  const int bh = ((id >> 6) << 3) | (id & 7);
  const int qt = (id >> 3) & 7;
  const int b = bh >> 4, h = bh & 15;
  const int q0 = qt * 128 + w * 16;
  const size_t base = (size_t)bh << 16;  // bh * SEQ * DKH

  bf16x8 qa[2];
#pragma unroll
  for (int c = 0; c < 2; ++c)
    qa[c] = *(const bf16x8*)&Qg[base + (size_t)(q0 + lr) * DKH + c * 32 + lg * 8];

  const f32x4 FZ = {0.f, 0.f, 0.f, 0.f};
  f32x4 o[4];
  float mrun[4], lrun[4];
#pragma unroll
  for (int g = 0; g < 4; ++g) { mrun[g] = -INFINITY; lrun[g] = 0.f; o[g] = FZ; }

  // prologue: stage tile 0 (512 threads x 16B = 8KB = one full tile each)
  {
    const int off = t * 8;
    const int hi = off >> 11, mid = (off >> 5) & 63, lo = off & 31;
    gload_lds16(&Kg[base + (size_t)mid * DKH + hi * 32 + lo], &Ks[0][off]);
    gload_lds16(&Vtg[base + (size_t)mid * SEQ + hi * 32 + lo], &Vs[0][off]);
  }
  asm volatile("s_waitcnt vmcnt(0)" ::: "memory");
  __syncthreads();

  int cur = 0;
  for (int kt = 0; kt < SEQ / 64; ++kt) {
    const int kv0 = kt * 64;
    // prefetch next KV tile into other buffer (flies under compute)
    if (kt + 1 < SEQ / 64) {
      const int off = t * 8;
      const int hi = off >> 11, mid = (off >> 5) & 63, lo = off & 31;
      gload_lds16(&Kg[base + (size_t)(kv0 + 64 + mid) * DKH + hi * 32 + lo], &Ks[cur ^ 1][off]);
      gload_lds16(&Vtg[base + (size_t)mid * SEQ + kv0 + 64 + hi * 32 + lo], &Vs[cur ^ 1][off]);
    }

    // QK^T (K-frags loaded per c-phase to keep VGPR live-set small)
    f32x4 s[4];
#pragma unroll
    for (int n = 0; n < 4; ++n) s[n] = FZ;
#pragma unroll
    for (int c = 0; c < 2; ++c) {
      bf16x8 kb[4];
#pragma unroll
      for (int n = 0; n < 4; ++n)
        kb[n] = *(const bf16x8*)&Ks[cur][c * 2048 + (n * 16 + lr) * 32 + lg * 8];
      __builtin_amdgcn_s_setprio(1);
#pragma unroll
      for (int n = 0; n < 4; ++n) s[n] = MFMA16(qa[c], kb[n], s[n]);
      __builtin_amdgcn_s_setprio(0);
    }

    // mask add
    float madd[4];
#pragma unroll
    for (int n = 0; n < 4; ++n)
      madd[n] = smask[(size_t)(kv0 + n * 16 + lr) * NB + b] ? -1e10f : 0.f;
#pragma unroll
    for (int n = 0; n < 4; ++n)
#pragma unroll
      for (int g = 0; g < 4; ++g) s[n][g] += madd[n];

    // online softmax per row (row = q0 + 4*lg + g; its 16 lanes differ in lane bits 0-3)
#pragma unroll
    for (int g = 0; g < 4; ++g) {
      float tm = fmaxf(fmaxf(s[0][g], s[1][g]), fmaxf(s[2][g], s[3][g]));
      tm = fmaxf(tm, __shfl_xor(tm, 1));
      tm = fmaxf(tm, __shfl_xor(tm, 2));
      tm = fmaxf(tm, __shfl_xor(tm, 4));
      tm = fmaxf(tm, __shfl_xor(tm, 8));
      const float mnew = fmaxf(mrun[g], tm);
      float ts = 0.f;
#pragma unroll
      for (int n = 0; n < 4; ++n) {
        const float p = __expf(s[n][g] - mnew);
        s[n][g] = p;
        ts += p;
      }
      ts += __shfl_xor(ts, 1);
      ts += __shfl_xor(ts, 2);
      ts += __shfl_xor(ts, 4);
      ts += __shfl_xor(ts, 8);
      const float sc = __expf(mrun[g] - mnew);
      lrun[g] = lrun[g] * sc + ts;
      mrun[g] = mnew;
#pragma unroll
      for (int n = 0; n < 4; ++n) o[n][g] *= sc;
    }

    // P: D-fragment layout -> LDS -> A-fragment layout (bf16), padded stride 72
    bf16* Pw = &Ps[w][0];
#pragma unroll
    for (int n = 0; n < 4; ++n)
#pragma unroll
      for (int g = 0; g < 4; ++g)
        Pw[(4 * lg + g) * 72 + n * 16 + lr] = (bf16)s[n][g];
    __builtin_amdgcn_sched_barrier(0);  // keep ds_reads after ds_writes

    // PV (V-frags loaded per c-phase)
#pragma unroll
    for (int c = 0; c < 2; ++c) {
      const bf16x8 pa = *(const bf16x8*)&Pw[lr * 72 + c * 32 + lg * 8];
      bf16x8 vb[4];
#pragma unroll
      for (int n = 0; n < 4; ++n)
        vb[n] = *(const bf16x8*)&Vs[cur][c * 2048 + (n * 16 + lr) * 32 + lg * 8];
      __builtin_amdgcn_s_setprio(1);
#pragma unroll
      for (int n = 0; n < 4; ++n) o[n] = MFMA16(pa, vb[n], o[n]);
      __builtin_amdgcn_s_setprio(0);
    }

    asm volatile("s_waitcnt vmcnt(0)" ::: "memory");
    __syncthreads();
    cur ^= 1;
  }

  // write attn output, token-major (l*NB+b, h*64+d), bf16
#pragma unroll
  for (int g = 0; g < 4; ++g) {
    const int l = q0 + 4 * lg + g;
    const float inv = 1.0f / lrun[g];
#pragma unroll
    for (int n = 0; n < 4; ++n)
      Og[(size_t)(l * NB + b) * DM + h * 64 + n * 16 + lr] = (bf16)(o[n][g] * inv);
  }
}

// ---------------- host orchestration ----------------
extern "C" void kernel_launch(void* const* d_in, const int* in_sizes, int n_in,
                              void* d_out, int out_size, void* d_ws, size_t ws_size,
                              hipStream_t stream) {
  const float* enc = (const float*)d_in[0];
  const float* emb = (const float*)d_in[1];
  const unsigned char* smask = (const unsigned char*)d_in[2];
  // d_in[3] tgt_mask, d_in[4..11] mmha_*, d_in[24..25] ln0_* are dead (sublayer 0 discarded)
  const float* wq = (const float*)d_in[12]; const float* bq = (const float*)d_in[13];
  const float* wk = (const float*)d_in[14]; const float* bk = (const float*)d_in[15];
  const float* wv = (const float*)d_in[16]; const float* bv = (const float*)d_in[17];
  const float* wo = (const float*)d_in[18]; const float* bo = (const float*)d_in[19];
  const float* w1 = (const float*)d_in[20]; const float* b1 = (const float*)d_in[21];
  const float* w2 = (const float*)d_in[22]; const float* b2 = (const float*)d_in[23];
  const float* g1 = (const float*)d_in[26]; const float* be1 = (const float*)d_in[27];
  const float* g2 = (const float*)d_in[28]; const float* be2 = (const float*)d_in[29];

  char* ws = (char*)d_ws;
  const size_t MB = (size_t)1 << 20;
  bf16* wqkv_bf = (bf16*)(ws + 0 * MB);   // 3072x1024 packed (Q|K|V)
  bf16* wo_bf   = (bf16*)(ws + 6 * MB);
  bf16* w1_bf   = (bf16*)(ws + 8 * MB);
  bf16* w2_bf   = (bf16*)(ws + 16 * MB);
  bf16* enc_bf  = (bf16*)(ws + 24 * MB);
  bf16* z_bf    = enc_bf;                 // alias: enc_bf dead after QKV proj
  bf16* qin_bf  = (bf16*)(ws + 32 * MB);
  bf16* attn_bf = qin_bf;                 // alias: qin dead after QKV proj
  bf16* Q_bf    = (bf16*)(ws + 40 * MB);
  bf16* K_bf    = (bf16*)(ws + 48 * MB);
  bf16* Vt_bf   = (bf16*)(ws + 56 * MB);
  float* encdec = (float*)(ws + 64 * MB);
  bf16* h_bf    = (bf16*)(ws + 80 * MB);

  // casts (f32 -> bf16): wq|wk|wv packed into wqkv, wo separate; w1, w2, enc
  cast4_kernel<<<4096, 256, 0, stream>>>(wq, wk, wv, wo,
                                         wqkv_bf, wqkv_bf + (1 << 20), wqkv_bf + (2 << 20), wo_bf);
  cast3_kernel<<<12288, 256, 0, stream>>>(w1, w2, enc, w1_bf, w2_bf, enc_bf);

  // LN1(embedded) -> q_in
  ln_kernel<<<4096, 256, 0, stream>>>(emb, g1, be1, qin_bf);

  // fused Q|K|V projection: N=3072, grid (32,24)=768 blocks (3/CU)
  {
    GParams p{qin_bf, enc_bf, wqkv_bf, bq, bk, bv, nullptr, Q_bf, K_bf, Vt_bf, 3072, DM};
    gemm2<EPI_QKV, 128, 32><<<dim3(32, 24), 256, 0, stream>>>(p);
  }

  // flash attention: 512 blocks x 512 threads (XCD-swizzled 1-D grid)
  attn_kernel<<<512, 512, 0, stream>>>(Q_bf, K_bf, Vt_bf, smask, attn_bf);

  // O projection + residual(embedded) -> enc_dec (f32)
  {
    GParams p{attn_bf, nullptr, wo_bf, bo, nullptr, nullptr, emb, encdec, nullptr, nullptr, DM, DM};
    gemm2<EPI_O, 64, 64><<<dim3(32, 16), 256, 0, stream>>>(p);
  }

  // LN2(enc_dec) -> z
  ln_kernel<<<4096, 256, 0, stream>>>(encdec, g2, be2, z_bf);

  // FFN
  {
    GParams p{z_bf, nullptr, w1_bf, b1, nullptr, nullptr, nullptr, h_bf, nullptr, nullptr, DF, DM};
    gemm2<EPI_F1, 128, 32><<<dim3(32, 32), 256, 0, stream>>>(p);
  }
  {
    GParams p{h_bf, nullptr, w2_bf, b2, nullptr, nullptr, encdec, d_out, nullptr, nullptr, DM, DF};
    gemm2<EPI_F2, 64, 64><<<dim3(32, 16), 256, 0, stream>>>(p);
  }
}